// Round 1
// baseline (99.214 us; speedup 1.0000x reference)
//
#include <hip/hip_runtime.h>
#include <math.h>

#define LOOP 100
#define BN_EPS 1e-5f

// Layout notes:
//  feats flat index f = k*16 + p  (k = scan step, p = pixel r*4+c)
//  feats[i][j] = flat[i*100 + j]  (pure reshape, NOT a transpose)
//  h1  = feats(16x100) @ w1^T(100x60) + b1 ; a1 = 2*swish(h1) - 1
//  h2  = swish(a1(16x60) @ w2^T + b2)      ; y = h2(16x16) @ w3^T + b3  -> (16,8)

__global__ __launch_bounds__(256) void model_kernel(
    const float* __restrict__ x,        // 16
    const float* __restrict__ conv_w,   // 9
    const float* __restrict__ conv_b,   // 1
    const float* __restrict__ bn_gamma, // 1
    const float* __restrict__ bn_beta,  // 1
    const float* __restrict__ bn_mean,  // 1
    const float* __restrict__ bn_var,   // 1
    const float* __restrict__ w1,       // 60*100
    const float* __restrict__ b1,       // 60
    const float* __restrict__ w2,       // 16*60
    const float* __restrict__ b2,       // 16
    const float* __restrict__ w3,       // 8*16
    const float* __restrict__ b3,       // 8
    float* __restrict__ out)            // 16*8
{
    __shared__ float s_feats[1600];   // 16 rows x 100
    __shared__ float s_w1[6000];      // 60 rows x 100
    __shared__ float s_w2[960];       // 16 rows x 60
    __shared__ float s_w3[128];       // 8 rows x 16
    __shared__ float s_b1[64];
    __shared__ float s_b2[16];
    __shared__ float s_b3[8];
    __shared__ float s_a1[960];       // 16 x 60
    __shared__ float s_h2[256];       // 16 x 16

    const int tid = threadIdx.x;

    if (tid < 64) {
        // ---- wave 0: sequential conv-scan, one lane per pixel ----
        const int p = tid;            // lanes 0..15 own pixels; 16..63 compute harmless garbage
        const int r = (p >> 2) & 3;
        const int c = p & 3;
        float xv = (p < 16) ? x[p] : 0.0f;

        float w[9];
        #pragma unroll
        for (int i = 0; i < 9; ++i) w[i] = conv_w[i];
        const float cb      = conv_b[0];
        const float inv_std = bn_gamma[0] / sqrtf(bn_var[0] + BN_EPS);
        const float shift   = bn_beta[0] - bn_mean[0] * inv_std;

        // precompute neighbor source lanes + validity masks (9 taps)
        int   src[9];
        float msk[9];
        #pragma unroll
        for (int dr = -1; dr <= 1; ++dr) {
            #pragma unroll
            for (int dc = -1; dc <= 1; ++dc) {
                int i  = (dr + 1) * 3 + (dc + 1);
                int rr = r + dr, ccc = c + dc;
                bool ok = (p < 16) && rr >= 0 && rr < 4 && ccc >= 0 && ccc < 4;
                src[i] = ok ? (rr * 4 + ccc) : p;
                msk[i] = ok ? 1.0f : 0.0f;
            }
        }

        for (int k = 0; k < LOOP; ++k) {
            float v[9];
            #pragma unroll
            for (int i = 0; i < 9; ++i)
                v[i] = __shfl(xv, src[i], 64) * msk[i];
            float a = cb;
            #pragma unroll
            for (int i = 0; i < 9; ++i) a = fmaf(w[i], v[i], a);
            // swish(a) = a * sigmoid(a); precise path (error amplifies over 100 steps)
            float t = expf(-a);
            float s = 1.0f / (1.0f + t);
            float b = fmaf(a * s, inv_std, shift);
            float h = a * b;
            float xn = copysignf(sqrtf(fabsf(h)), h);
            if (p < 16) s_feats[k * 16 + p] = xn;
            xv = xn;
        }
    } else {
        // ---- waves 1..3 (192 threads): prefetch MLP weights into LDS ----
        const int t = tid - 64;
        const float4* w1v = reinterpret_cast<const float4*>(w1);
        float4*       s1v = reinterpret_cast<float4*>(s_w1);
        for (int i = t; i < 1500; i += 192) s1v[i] = w1v[i];
        const float4* w2v = reinterpret_cast<const float4*>(w2);
        float4*       s2v = reinterpret_cast<float4*>(s_w2);
        for (int i = t; i < 240; i += 192) s2v[i] = w2v[i];
        if (t < 128) s_w3[t] = w3[t];
        if (t < 60)  s_b1[t] = b1[t];
        if (t < 16)  s_b2[t] = b2[t];
        if (t < 8)   s_b3[t] = b3[t];
    }
    __syncthreads();

    // ---- Stage A: h1 = feats @ w1^T + b1 ; a1 = 2*swish(h1) - 1 ----
    for (int q = tid; q < 960; q += 256) {
        int i = q / 60;
        int o = q - i * 60;
        const float4* fr = reinterpret_cast<const float4*>(&s_feats[i * 100]);
        const float4* wr = reinterpret_cast<const float4*>(&s_w1[o * 100]);
        float ax = 0.f, ay = 0.f, az = 0.f, aw = 0.f;
        #pragma unroll
        for (int j = 0; j < 25; ++j) {
            float4 f = fr[j], g = wr[j];
            ax = fmaf(f.x, g.x, ax);
            ay = fmaf(f.y, g.y, ay);
            az = fmaf(f.z, g.z, az);
            aw = fmaf(f.w, g.w, aw);
        }
        float acc = s_b1[o] + ((ax + ay) + (az + aw));
        float s = 1.0f / (1.0f + __expf(-acc));
        s_a1[q] = 2.0f * acc * s - 1.0f;
    }
    __syncthreads();

    // ---- Stage B: h2 = swish(a1 @ w2^T + b2) ---- (exactly 256 outputs)
    {
        int i = tid >> 4;
        int o = tid & 15;
        const float4* ar = reinterpret_cast<const float4*>(&s_a1[i * 60]);
        const float4* wr = reinterpret_cast<const float4*>(&s_w2[o * 60]);
        float ax = 0.f, ay = 0.f, az = 0.f, aw = 0.f;
        #pragma unroll
        for (int j = 0; j < 15; ++j) {
            float4 f = ar[j], g = wr[j];
            ax = fmaf(f.x, g.x, ax);
            ay = fmaf(f.y, g.y, ay);
            az = fmaf(f.z, g.z, az);
            aw = fmaf(f.w, g.w, aw);
        }
        float acc = s_b2[o] + ((ax + ay) + (az + aw));
        float s = 1.0f / (1.0f + __expf(-acc));
        s_h2[tid] = acc * s;
    }
    __syncthreads();

    // ---- Stage C: y = h2 @ w3^T + b3 ---- (128 outputs)
    if (tid < 128) {
        int i = tid >> 3;
        int o = tid & 7;
        const float4* hr = reinterpret_cast<const float4*>(&s_h2[i * 16]);
        const float4* wr = reinterpret_cast<const float4*>(&s_w3[o * 16]);
        float ax = 0.f, ay = 0.f, az = 0.f, aw = 0.f;
        #pragma unroll
        for (int j = 0; j < 4; ++j) {
            float4 f = hr[j], g = wr[j];
            ax = fmaf(f.x, g.x, ax);
            ay = fmaf(f.y, g.y, ay);
            az = fmaf(f.z, g.z, az);
            aw = fmaf(f.w, g.w, aw);
        }
        out[i * 8 + o] = s_b3[o] + ((ax + ay) + (az + aw));
    }
}

extern "C" void kernel_launch(void* const* d_in, const int* in_sizes, int n_in,
                              void* d_out, int out_size, void* d_ws, size_t ws_size,
                              hipStream_t stream) {
    const float* x        = (const float*)d_in[0];
    const float* conv_w   = (const float*)d_in[1];
    const float* conv_b   = (const float*)d_in[2];
    const float* bn_gamma = (const float*)d_in[3];
    const float* bn_beta  = (const float*)d_in[4];
    const float* bn_mean  = (const float*)d_in[5];
    const float* bn_var   = (const float*)d_in[6];
    const float* w1       = (const float*)d_in[7];
    const float* b1       = (const float*)d_in[8];
    const float* w2       = (const float*)d_in[9];
    const float* b2       = (const float*)d_in[10];
    const float* w3       = (const float*)d_in[11];
    const float* b3       = (const float*)d_in[12];
    float* out = (float*)d_out;

    model_kernel<<<1, 256, 0, stream>>>(x, conv_w, conv_b, bn_gamma, bn_beta,
                                        bn_mean, bn_var, w1, b1, w2, b2, w3, b3, out);
}

// Round 2
// 85.614 us; speedup vs baseline: 1.1589x; 1.1589x over previous
//
#include <hip/hip_runtime.h>
#include <math.h>

#define LOOP 100
#define BN_EPS 1e-5f

// DPP lane-shift within rows of 16 lanes, zero-fill at row boundary.
// row_shr:N -> dest[i] = src[i-N]  (ctrl 0x110|N)
// row_shl:N -> dest[i] = src[i+N]  (ctrl 0x100|N)
#define DPPF(v, ctrl) \
    __int_as_float(__builtin_amdgcn_update_dpp(0, __float_as_int(v), (ctrl), 0xF, 0xF, true))

// Layout notes:
//  feats flat index f = k*16 + p  (k = scan step, p = pixel r*4+c)
//  feats[i][j] = flat[i*100 + j]  (pure reshape, NOT a transpose)
//  h1  = feats(16x100) @ w1^T(100x60) + b1 ; a1 = 2*swish(h1) - 1
//  h2  = swish(a1(16x60) @ w2^T + b2)      ; y = h2(16x16) @ w3^T + b3  -> (16,8)

__global__ __launch_bounds__(256) void model_kernel(
    const float* __restrict__ x,        // 16
    const float* __restrict__ conv_w,   // 9
    const float* __restrict__ conv_b,   // 1
    const float* __restrict__ bn_gamma, // 1
    const float* __restrict__ bn_beta,  // 1
    const float* __restrict__ bn_mean,  // 1
    const float* __restrict__ bn_var,   // 1
    const float* __restrict__ w1,       // 60*100
    const float* __restrict__ b1,       // 60
    const float* __restrict__ w2,       // 16*60
    const float* __restrict__ b2,       // 16
    const float* __restrict__ w3,       // 8*16
    const float* __restrict__ b3,       // 8
    float* __restrict__ out)            // 16*8
{
    __shared__ __align__(16) float s_feats[1664];  // 100 steps x 16 px (+pad: lanes 16..63 spill harmlessly)
    __shared__ __align__(16) float s_w1[6000];     // 60 x 100
    __shared__ __align__(16) float s_w2[960];      // 16 x 60
    __shared__ __align__(16) float s_w3[128];      // 8 x 16
    __shared__ __align__(16) float s_b1[64];
    __shared__ __align__(16) float s_b2[16];
    __shared__ __align__(16) float s_b3[8];
    __shared__ __align__(16) float s_a1[960];      // 16 x 60
    __shared__ __align__(16) float s_h2[256];      // 16 x 16

    const int tid = threadIdx.x;

    if (tid < 64) {
        // ---- wave 0: sequential conv-scan, one lane per pixel (lanes 0..15) ----
        const int p = tid;
        const int r = (p >> 2) & 3;
        const int c = p & 3;
        float xv = (p < 16) ? x[p] : 0.0f;

        const float cb      = conv_b[0];
        const float inv_std = bn_gamma[0] / sqrtf(bn_var[0] + BN_EPS);
        const float shift   = bn_beta[0] - bn_mean[0] * inv_std;

        // premask conv weights per lane: wm[i] = w[i] * valid(i)
        float wm[9];
        #pragma unroll
        for (int dr = -1; dr <= 1; ++dr) {
            #pragma unroll
            for (int dc = -1; dc <= 1; ++dc) {
                int i  = (dr + 1) * 3 + (dc + 1);
                int rr = r + dr, cc2 = c + dc;
                bool ok = (p < 16) && rr >= 0 && rr < 4 && cc2 >= 0 && cc2 < 4;
                wm[i] = ok ? conv_w[i] : 0.0f;
            }
        }

        for (int k = 0; k < LOOP; ++k) {
            // neighbor taps via DPP row shifts (row of 16 lanes == the 16 pixels)
            float vm5 = DPPF(xv, 0x115);  // src lane p-5  (dr=-1,dc=-1)
            float vm4 = DPPF(xv, 0x114);  // p-4           (dr=-1,dc= 0)
            float vm3 = DPPF(xv, 0x113);  // p-3           (dr=-1,dc=+1)
            float vm1 = DPPF(xv, 0x111);  // p-1           (dr= 0,dc=-1)
            float vp1 = DPPF(xv, 0x101);  // p+1           (dr= 0,dc=+1)
            float vp3 = DPPF(xv, 0x103);  // p+3           (dr=+1,dc=-1)
            float vp4 = DPPF(xv, 0x104);  // p+4           (dr=+1,dc= 0)
            float vp5 = DPPF(xv, 0x105);  // p+5           (dr=+1,dc=+1)

            // 3 parallel FMA chains, depth 3
            float a0 = fmaf(wm[0], vm5, cb);
            a0 = fmaf(wm[3], vm1, a0);
            a0 = fmaf(wm[6], vp3, a0);
            float a1 = wm[1] * vm4;
            a1 = fmaf(wm[4], xv, a1);
            a1 = fmaf(wm[7], vp4, a1);
            float a2 = wm[2] * vm3;
            a2 = fmaf(wm[5], vp1, a2);
            a2 = fmaf(wm[8], vp5, a2);
            float a = (a0 + a1) + a2;

            // h = a * (swish(a)*inv_std + shift) = (a^2*inv_std)*sigmoid(a) + a*shift
            float e   = __expf(-a);                       // v_exp path
            float s   = __builtin_amdgcn_rcpf(1.0f + e);  // v_rcp, no refine
            float t2  = a * a * inv_std;                  // runs parallel to exp
            float ash = a * shift;
            float h   = fmaf(t2, s, ash);
            float xn  = copysignf(__builtin_amdgcn_sqrtf(__builtin_fabsf(h)), h);

            s_feats[k * 16 + p] = xn;   // all 64 lanes write; p>=16 lands in pad
            xv = xn;
        }
    } else {
        // ---- waves 1..3 (192 threads): prefetch MLP weights into LDS ----
        const int t = tid - 64;
        const float4* w1v = reinterpret_cast<const float4*>(w1);
        float4*       s1v = reinterpret_cast<float4*>(s_w1);
        for (int i = t; i < 1500; i += 192) s1v[i] = w1v[i];
        const float4* w2v = reinterpret_cast<const float4*>(w2);
        float4*       s2v = reinterpret_cast<float4*>(s_w2);
        for (int i = t; i < 240; i += 192) s2v[i] = w2v[i];
        if (t < 128) s_w3[t] = w3[t];
        if (t < 60)  s_b1[t] = b1[t];
        if (t < 16)  s_b2[t] = b2[t];
        if (t < 8)   s_b3[t] = b3[t];
    }
    __syncthreads();

    // ---- Stage A: h1 = feats @ w1^T + b1 ; a1 = 2*swish(h1) - 1 ----
    // 240 threads, 4 outputs each: i = t/15, o = oq + {0,15,30,45} (stride-15 keeps banks spread)
    if (tid < 240) {
        const int i  = tid / 15;
        const int oq = tid - i * 15;
        const float4* fr = reinterpret_cast<const float4*>(&s_feats[i * 100]);
        const float4* g[4] = {
            reinterpret_cast<const float4*>(&s_w1[(oq     ) * 100]),
            reinterpret_cast<const float4*>(&s_w1[(oq + 15) * 100]),
            reinterpret_cast<const float4*>(&s_w1[(oq + 30) * 100]),
            reinterpret_cast<const float4*>(&s_w1[(oq + 45) * 100]) };
        float ax[4] = {0,0,0,0}, ay[4] = {0,0,0,0}, az[4] = {0,0,0,0}, aw[4] = {0,0,0,0};
        #pragma unroll
        for (int j = 0; j < 25; ++j) {
            float4 f = fr[j];
            #pragma unroll
            for (int kk = 0; kk < 4; ++kk) {
                float4 gg = g[kk][j];
                ax[kk] = fmaf(f.x, gg.x, ax[kk]);
                ay[kk] = fmaf(f.y, gg.y, ay[kk]);
                az[kk] = fmaf(f.z, gg.z, az[kk]);
                aw[kk] = fmaf(f.w, gg.w, aw[kk]);
            }
        }
        #pragma unroll
        for (int kk = 0; kk < 4; ++kk) {
            int o = oq + 15 * kk;
            float acc = s_b1[o] + ((ax[kk] + ay[kk]) + (az[kk] + aw[kk]));
            float s = __builtin_amdgcn_rcpf(1.0f + __expf(-acc));
            s_a1[i * 60 + o] = 2.0f * acc * s - 1.0f;
        }
    }
    __syncthreads();

    // ---- Stage B: h2 = swish(a1 @ w2^T + b2) ---- (exactly 256 outputs)
    {
        int i = tid >> 4;
        int o = tid & 15;
        const float4* ar = reinterpret_cast<const float4*>(&s_a1[i * 60]);
        const float4* wr = reinterpret_cast<const float4*>(&s_w2[o * 60]);
        float ax = 0.f, ay = 0.f, az = 0.f, aw = 0.f;
        #pragma unroll
        for (int j = 0; j < 15; ++j) {
            float4 f = ar[j], gg = wr[j];
            ax = fmaf(f.x, gg.x, ax);
            ay = fmaf(f.y, gg.y, ay);
            az = fmaf(f.z, gg.z, az);
            aw = fmaf(f.w, gg.w, aw);
        }
        float acc = s_b2[o] + ((ax + ay) + (az + aw));
        float s = __builtin_amdgcn_rcpf(1.0f + __expf(-acc));
        s_h2[tid] = acc * s;
    }
    __syncthreads();

    // ---- Stage C: y = h2 @ w3^T + b3 ---- (128 outputs)
    if (tid < 128) {
        int i = tid >> 3;
        int o = tid & 7;
        const float4* hr = reinterpret_cast<const float4*>(&s_h2[i * 16]);
        const float4* wr = reinterpret_cast<const float4*>(&s_w3[o * 16]);
        float ax = 0.f, ay = 0.f, az = 0.f, aw = 0.f;
        #pragma unroll
        for (int j = 0; j < 4; ++j) {
            float4 f = hr[j], gg = wr[j];
            ax = fmaf(f.x, gg.x, ax);
            ay = fmaf(f.y, gg.y, ay);
            az = fmaf(f.z, gg.z, az);
            aw = fmaf(f.w, gg.w, aw);
        }
        out[i * 8 + o] = s_b3[o] + ((ax + ay) + (az + aw));
    }
}

extern "C" void kernel_launch(void* const* d_in, const int* in_sizes, int n_in,
                              void* d_out, int out_size, void* d_ws, size_t ws_size,
                              hipStream_t stream) {
    const float* x        = (const float*)d_in[0];
    const float* conv_w   = (const float*)d_in[1];
    const float* conv_b   = (const float*)d_in[2];
    const float* bn_gamma = (const float*)d_in[3];
    const float* bn_beta  = (const float*)d_in[4];
    const float* bn_mean  = (const float*)d_in[5];
    const float* bn_var   = (const float*)d_in[6];
    const float* w1       = (const float*)d_in[7];
    const float* b1       = (const float*)d_in[8];
    const float* w2       = (const float*)d_in[9];
    const float* b2       = (const float*)d_in[10];
    const float* w3       = (const float*)d_in[11];
    const float* b3       = (const float*)d_in[12];
    float* out = (float*)d_out;

    model_kernel<<<1, 256, 0, stream>>>(x, conv_w, conv_b, bn_gamma, bn_beta,
                                        bn_mean, bn_var, w1, b1, w2, b2, w3, b3, out);
}